// Round 1
// baseline (261.408 us; speedup 1.0000x reference)
//
#include <hip/hip_runtime.h>

// Aggregationlayer: coord = clip(x) + mean_k clip(trans)
//                   h = hh + silu([hh | sum_k ef] @ W1 + b1) @ W2 + b2
// Fused single kernel, memory-bound on edge_feature (819 MB).
// MLP done with mfma_f32_16x16x32_bf16 (f32 accumulate) so compute hides
// under the streaming reduction.

typedef float f32x4 __attribute__((ext_vector_type(4)));
typedef short short8 __attribute__((ext_vector_type(8)));
typedef short short4v __attribute__((ext_vector_type(4)));

#define MT 32          // rows per block
#define KNB 16         // K neighbors
#define HNF 256        // feature width

__device__ __forceinline__ short f2bf(float f) {
  unsigned u = __builtin_bit_cast(unsigned, f);
  u += 0x7fffu + ((u >> 16) & 1u);   // round-to-nearest-even
  return (short)(u >> 16);
}

__device__ __forceinline__ float clipf(float v) {
  return fminf(fmaxf(v, -1000.f), 1000.f);
}

// Load a 32x16 B-fragment column slice from an f32 weight matrix (256 cols),
// converting to bf16. lane holds W[k0..k0+7][col].
__device__ __forceinline__ short8 load_wfrag(const float* __restrict__ W, int k0, int col) {
  short8 r;
#pragma unroll
  for (int j = 0; j < 8; ++j) r[j] = f2bf(W[(size_t)(k0 + j) * 256 + col]);
  return r;
}

__global__ __launch_bounds__(256, 4) void agg_fused(
    const float* __restrict__ x, const float* __restrict__ trans,
    const float* __restrict__ edge, const float* __restrict__ hh,
    const float* __restrict__ W1, const float* __restrict__ b1,
    const float* __restrict__ W2, const float* __restrict__ b2,
    float* __restrict__ coord_out, float* __restrict__ h_out, int N) {
  // agg tile [MT][512] bf16, XOR-swizzled (row stride 1024 B). 32 KB.
  // After mat1 it is reused for T [MT][256] bf16 (row stride 512 B).
  __shared__ __align__(16) char smem[MT * 512 * 2];

  const int t = threadIdx.x;
  const int w = t >> 6;        // wave 0..3
  const int lane = t & 63;
  const int r0 = blockIdx.x * MT;

  // ---------------- coord output (f32 exact) ----------------
  if (t < MT) {
    int grow = r0 + t;
    if (grow < N) {
      float cx[3], s[3];
#pragma unroll
      for (int d = 0; d < 3; ++d) { cx[d] = clipf(x[(size_t)grow * 3 + d]); s[d] = 0.f; }
      const float* tp = trans + (size_t)grow * 48;   // K*3 = 48 floats, 16B aligned
#pragma unroll
      for (int q = 0; q < 12; ++q) {
        f32x4 v = *(const f32x4*)(tp + q * 4);
#pragma unroll
        for (int e = 0; e < 4; ++e) s[(q * 4 + e) % 3] += clipf(v[e]);
      }
#pragma unroll
      for (int d = 0; d < 3; ++d)
        coord_out[(size_t)grow * 3 + d] = cx[d] + s[d] * (1.f / 16.f);
    }
  }

  // ---------------- stage agg = [hh | sum_k edge] as bf16 ----------------
  // wave w handles row i0+w; 64 lanes cover 256 cols as float4.
#pragma unroll
  for (int i0 = 0; i0 < MT; i0 += 4) {
    int row = i0 + w;
    int grow = r0 + row;
    f32x4 ef = {0.f, 0.f, 0.f, 0.f};
    f32x4 hv = {0.f, 0.f, 0.f, 0.f};
    if (grow < N) {
      const float* ep = edge + (size_t)grow * (KNB * HNF) + lane * 4;
#pragma unroll
      for (int k = 0; k < KNB; ++k) {
        f32x4 v = *(const f32x4*)(ep + k * HNF);
        ef += v;
      }
      hv = *(const f32x4*)(hh + (size_t)grow * HNF + lane * 4);
    }
    short4v hb, eb;
#pragma unroll
    for (int j = 0; j < 4; ++j) { hb[j] = f2bf(hv[j]); eb[j] = f2bf(ef[j]); }
    int sw = (row & 7) << 4;
    *(short4v*)(smem + ((row * 1024 + lane * 8) ^ sw)) = hb;          // cols 0..255 = hh
    *(short4v*)(smem + ((row * 1024 + 512 + lane * 8) ^ sw)) = eb;    // cols 256..511 = ef
  }
  __syncthreads();

  // ---------------- mat1: T = silu(agg @ W1 + b1) ----------------
  const int colbase = w * 64;          // each wave owns 64 output cols
  const int mrow = lane & 15;          // A-fragment row within 16-tile
  const int kgrp = (lane >> 4) * 8;    // k offset within 32-step
  const int ncol = lane & 15;          // B-fragment / C col within 16-tile

  f32x4 acc1[2][4];
#pragma unroll
  for (int mt = 0; mt < 2; ++mt)
#pragma unroll
    for (int nt = 0; nt < 4; ++nt) acc1[mt][nt] = (f32x4){0.f, 0.f, 0.f, 0.f};

#pragma unroll 2
  for (int kk = 0; kk < 16; ++kk) {
    int k0 = kk * 32 + kgrp;
    int swa = (mrow & 7) << 4;
    short8 a0 = *(const short8*)(smem + ((mrow * 1024 + k0 * 2) ^ swa));
    short8 a1 = *(const short8*)(smem + (((16 + mrow) * 1024 + k0 * 2) ^ swa));
    short8 bf[4];
#pragma unroll
    for (int nt = 0; nt < 4; ++nt) bf[nt] = load_wfrag(W1, k0, colbase + nt * 16 + ncol);
#pragma unroll
    for (int nt = 0; nt < 4; ++nt) {
      acc1[0][nt] = __builtin_amdgcn_mfma_f32_16x16x32_bf16(a0, bf[nt], acc1[0][nt], 0, 0, 0);
      acc1[1][nt] = __builtin_amdgcn_mfma_f32_16x16x32_bf16(a1, bf[nt], acc1[1][nt], 0, 0, 0);
    }
  }

  float b1v[4];
#pragma unroll
  for (int nt = 0; nt < 4; ++nt) b1v[nt] = b1[colbase + nt * 16 + ncol];

  __syncthreads();   // everyone done reading agg before we overwrite with T

  // silu in f32, write T bf16 into reused smem: T[row][col], row stride 512 B
#pragma unroll
  for (int mt = 0; mt < 2; ++mt)
#pragma unroll
    for (int nt = 0; nt < 4; ++nt)
#pragma unroll
      for (int r = 0; r < 4; ++r) {
        float v = acc1[mt][nt][r] + b1v[nt];
        v = v / (1.f + __expf(-v));
        int row = mt * 16 + (lane >> 4) * 4 + r;   // C/D: row=(lane>>4)*4+reg
        int col = colbase + nt * 16 + ncol;        // C/D: col=lane&15
        int off = (row * 512 + col * 2) ^ ((row & 7) << 4);
        *(short*)(smem + off) = f2bf(v);
      }
  __syncthreads();

  // ---------------- mat2: h = T @ W2 + b2 + hh ----------------
  f32x4 acc2[2][4];
#pragma unroll
  for (int mt = 0; mt < 2; ++mt)
#pragma unroll
    for (int nt = 0; nt < 4; ++nt) acc2[mt][nt] = (f32x4){0.f, 0.f, 0.f, 0.f};

#pragma unroll 2
  for (int kk = 0; kk < 8; ++kk) {
    int k0 = kk * 32 + kgrp;
    int swa = (mrow & 7) << 4;
    short8 a0 = *(const short8*)(smem + ((mrow * 512 + k0 * 2) ^ swa));
    short8 a1 = *(const short8*)(smem + (((16 + mrow) * 512 + k0 * 2) ^ swa));
    short8 bf[4];
#pragma unroll
    for (int nt = 0; nt < 4; ++nt) bf[nt] = load_wfrag(W2, k0, colbase + nt * 16 + ncol);
#pragma unroll
    for (int nt = 0; nt < 4; ++nt) {
      acc2[0][nt] = __builtin_amdgcn_mfma_f32_16x16x32_bf16(a0, bf[nt], acc2[0][nt], 0, 0, 0);
      acc2[1][nt] = __builtin_amdgcn_mfma_f32_16x16x32_bf16(a1, bf[nt], acc2[1][nt], 0, 0, 0);
    }
  }

#pragma unroll
  for (int mt = 0; mt < 2; ++mt)
#pragma unroll
    for (int nt = 0; nt < 4; ++nt) {
      int col = colbase + nt * 16 + ncol;
      float bv = b2[col];
#pragma unroll
      for (int r = 0; r < 4; ++r) {
        int row = mt * 16 + (lane >> 4) * 4 + r;
        int grow = r0 + row;
        if (grow < N) {
          size_t idx = (size_t)grow * HNF + col;
          h_out[idx] = acc2[mt][nt][r] + bv + hh[idx];   // f32 residual
        }
      }
    }
}

extern "C" void kernel_launch(void* const* d_in, const int* in_sizes, int n_in,
                              void* d_out, int out_size, void* d_ws, size_t ws_size,
                              hipStream_t stream) {
  const float* x     = (const float*)d_in[0];
  const float* trans = (const float*)d_in[1];
  const float* edge  = (const float*)d_in[2];
  const float* hh    = (const float*)d_in[3];
  const float* W1    = (const float*)d_in[4];
  const float* b1    = (const float*)d_in[5];
  const float* W2    = (const float*)d_in[6];
  const float* b2    = (const float*)d_in[7];

  int N = in_sizes[0] / 3;
  float* coord_out = (float*)d_out;
  float* h_out = coord_out + (size_t)N * 3;

  int grid = (N + MT - 1) / MT;
  agg_fused<<<grid, 256, 0, stream>>>(x, trans, edge, hh, W1, b1, W2, b2,
                                      coord_out, h_out, N);
}

// Round 2
// 199.528 us; speedup vs baseline: 1.3101x; 1.3101x over previous
//
#include <hip/hip_runtime.h>

// Aggregationlayer: coord = clip(x) + mean_k clip(trans)
//                   h = hh + silu([hh | sum_k ef] @ W1 + b1) @ W2 + b2
// Fused kernel, memory-bound on edge_feature (819 MB).
// R1: weights pre-converted to bf16 fragment layout in d_ws (one dwordx4 per
//     fragment instead of 8 scalar f32 loads + VALU cvt); edge loads
//     non-temporal so hh/W stay L2-resident.

typedef float f32x4 __attribute__((ext_vector_type(4)));
typedef short short8 __attribute__((ext_vector_type(8)));
typedef short short4v __attribute__((ext_vector_type(4)));

#define MT 32          // rows per block
#define KNB 16         // K neighbors
#define HNF 256        // feature width
#define W1ELEMS (512 * 256)
#define W2ELEMS (256 * 256)
#define WS_NEEDED ((W1ELEMS + W2ELEMS) * sizeof(short))

__device__ __forceinline__ short f2bf(float f) {
  unsigned u = __builtin_bit_cast(unsigned, f);
  u += 0x7fffu + ((u >> 16) & 1u);   // round-to-nearest-even
  return (short)(u >> 16);
}

__device__ __forceinline__ float clipf(float v) {
  return fminf(fmaxf(v, -1000.f), 1000.f);
}

__device__ __forceinline__ f32x4 ldnt4(const float* p) {
  return __builtin_nontemporal_load((const f32x4*)p);
}

// Fallback: load a 32x16 B-fragment from f32 weights, converting inline.
__device__ __forceinline__ short8 load_wfrag(const float* __restrict__ W, int k0, int col) {
  short8 r;
#pragma unroll
  for (int j = 0; j < 8; ++j) r[j] = f2bf(W[(size_t)(k0 + j) * 256 + col]);
  return r;
}

// ---- pre-kernel: f32 weights -> bf16 fragment layout -----------------------
// dst[( (k>>5)*256 + col )*32 + ((k>>3)&3)*8 + (k&7)] = bf16(W[k][col])
// so an MFMA B-fragment (kk, col, kslot) is 8 contiguous shorts (16 B), and a
// wave's 4x16-col fragment group is one contiguous, fully-used 1 KB region.
__global__ void convw(const float* __restrict__ W1, const float* __restrict__ W2,
                      short* __restrict__ wb) {
  int i = blockIdx.x * 256 + threadIdx.x;
  const float* src; short* dst; int k, col;
  if (i < W1ELEMS) { src = W1; dst = wb; k = i >> 8; col = i & 255; }
  else             { int j = i - W1ELEMS; src = W2; dst = wb + W1ELEMS; k = j >> 8; col = j & 255; }
  short v = f2bf(src[((size_t)k << 8) | col]);
  dst[(((k >> 5) * 256 + col) << 5) + ((k >> 3) & 3) * 8 + (k & 7)] = v;
}

template <bool PRE>
__global__ __launch_bounds__(256, 4) void agg_fused(
    const float* __restrict__ x, const float* __restrict__ trans,
    const float* __restrict__ edge, const float* __restrict__ hh,
    const float* __restrict__ W1, const float* __restrict__ b1,
    const float* __restrict__ W2, const float* __restrict__ b2,
    const short* __restrict__ wb,
    float* __restrict__ coord_out, float* __restrict__ h_out, int N) {
  // agg tile [MT][512] bf16, XOR-swizzled (row stride 1024 B). 32 KB.
  // After mat1 it is reused for T [MT][256] bf16 (row stride 512 B).
  __shared__ __align__(16) char smem[MT * 512 * 2];

  const int t = threadIdx.x;
  const int w = t >> 6;        // wave 0..3
  const int lane = t & 63;
  const int r0 = blockIdx.x * MT;

  // ---------------- coord output (f32 exact), spread over all 4 waves -------
  if (lane < 8) {
    int row = w * 8 + lane;
    int grow = r0 + row;
    if (grow < N) {
      float cx[3], s[3];
#pragma unroll
      for (int d = 0; d < 3; ++d) { cx[d] = clipf(x[(size_t)grow * 3 + d]); s[d] = 0.f; }
      const float* tp = trans + (size_t)grow * 48;   // K*3 = 48 floats, 16B aligned
#pragma unroll
      for (int q = 0; q < 12; ++q) {
        f32x4 v = *(const f32x4*)(tp + q * 4);
#pragma unroll
        for (int e = 0; e < 4; ++e) s[(q * 4 + e) % 3] += clipf(v[e]);
      }
#pragma unroll
      for (int d = 0; d < 3; ++d)
        coord_out[(size_t)grow * 3 + d] = cx[d] + s[d] * (1.f / 16.f);
    }
  }

  // ---------------- stage agg = [hh | sum_k edge] as bf16 ----------------
  // wave w handles row i0+w; 64 lanes cover 256 cols as float4.
#pragma unroll
  for (int i0 = 0; i0 < MT; i0 += 4) {
    int row = i0 + w;
    int grow = r0 + row;
    f32x4 ef = {0.f, 0.f, 0.f, 0.f};
    f32x4 hv = {0.f, 0.f, 0.f, 0.f};
    if (grow < N) {
      const float* ep = edge + (size_t)grow * (KNB * HNF) + lane * 4;
#pragma unroll
      for (int k = 0; k < KNB; ++k) ef += ldnt4(ep + k * HNF);   // non-temporal
      hv = *(const f32x4*)(hh + (size_t)grow * HNF + lane * 4);
    }
    short4v hb, eb;
#pragma unroll
    for (int j = 0; j < 4; ++j) { hb[j] = f2bf(hv[j]); eb[j] = f2bf(ef[j]); }
    int sw = (row & 7) << 4;
    *(short4v*)(smem + ((row * 1024 + lane * 8) ^ sw)) = hb;          // cols 0..255 = hh
    *(short4v*)(smem + ((row * 1024 + 512 + lane * 8) ^ sw)) = eb;    // cols 256..511 = ef
  }
  __syncthreads();

  // ---------------- mat1: T = silu(agg @ W1 + b1) ----------------
  const int colbase = w * 64;          // each wave owns 64 output cols
  const int mrow = lane & 15;          // A-fragment row within 16-tile
  const int kslot = lane >> 4;         // which 8-k group within 32-step
  const int kgrp = kslot * 8;
  const int ncol = lane & 15;          // B-fragment / C col within 16-tile

  const short8* wf1 = (const short8*)(wb);                 // W1 fragments
  const short8* wf2 = (const short8*)(wb + W1ELEMS);       // W2 fragments

  f32x4 acc1[2][4];
#pragma unroll
  for (int mt = 0; mt < 2; ++mt)
#pragma unroll
    for (int nt = 0; nt < 4; ++nt) acc1[mt][nt] = (f32x4){0.f, 0.f, 0.f, 0.f};

#pragma unroll 2
  for (int kk = 0; kk < 16; ++kk) {
    int k0 = kk * 32 + kgrp;
    int swa = (mrow & 7) << 4;
    short8 a0 = *(const short8*)(smem + ((mrow * 1024 + k0 * 2) ^ swa));
    short8 a1 = *(const short8*)(smem + (((16 + mrow) * 1024 + k0 * 2) ^ swa));
    short8 bfr[4];
    if constexpr (PRE) {
      const short8* base = wf1 + ((kk * 256 + colbase + ncol) * 4 + kslot);
#pragma unroll
      for (int nt = 0; nt < 4; ++nt) bfr[nt] = base[nt * 64];   // +16 cols = +64 frags
    } else {
#pragma unroll
      for (int nt = 0; nt < 4; ++nt) bfr[nt] = load_wfrag(W1, k0, colbase + nt * 16 + ncol);
    }
#pragma unroll
    for (int nt = 0; nt < 4; ++nt) {
      acc1[0][nt] = __builtin_amdgcn_mfma_f32_16x16x32_bf16(a0, bfr[nt], acc1[0][nt], 0, 0, 0);
      acc1[1][nt] = __builtin_amdgcn_mfma_f32_16x16x32_bf16(a1, bfr[nt], acc1[1][nt], 0, 0, 0);
    }
  }

  float b1v[4];
#pragma unroll
  for (int nt = 0; nt < 4; ++nt) b1v[nt] = b1[colbase + nt * 16 + ncol];

  __syncthreads();   // everyone done reading agg before we overwrite with T

  // silu in f32, write T bf16 into reused smem: T[row][col], row stride 512 B
#pragma unroll
  for (int mt = 0; mt < 2; ++mt)
#pragma unroll
    for (int nt = 0; nt < 4; ++nt)
#pragma unroll
      for (int r = 0; r < 4; ++r) {
        float v = acc1[mt][nt][r] + b1v[nt];
        v = v / (1.f + __expf(-v));
        int row = mt * 16 + (lane >> 4) * 4 + r;   // C/D: row=(lane>>4)*4+reg
        int col = colbase + nt * 16 + ncol;        // C/D: col=lane&15
        int off = (row * 512 + col * 2) ^ ((row & 7) << 4);
        *(short*)(smem + off) = f2bf(v);
      }
  __syncthreads();

  // ---------------- mat2: h = T @ W2 + b2 + hh ----------------
  f32x4 acc2[2][4];
#pragma unroll
  for (int mt = 0; mt < 2; ++mt)
#pragma unroll
    for (int nt = 0; nt < 4; ++nt) acc2[mt][nt] = (f32x4){0.f, 0.f, 0.f, 0.f};

#pragma unroll 2
  for (int kk = 0; kk < 8; ++kk) {
    int k0 = kk * 32 + kgrp;
    int swa = (mrow & 7) << 4;
    short8 a0 = *(const short8*)(smem + ((mrow * 512 + k0 * 2) ^ swa));
    short8 a1 = *(const short8*)(smem + (((16 + mrow) * 512 + k0 * 2) ^ swa));
    short8 bfr[4];
    if constexpr (PRE) {
      const short8* base = wf2 + ((kk * 256 + colbase + ncol) * 4 + kslot);
#pragma unroll
      for (int nt = 0; nt < 4; ++nt) bfr[nt] = base[nt * 64];
    } else {
#pragma unroll
      for (int nt = 0; nt < 4; ++nt) bfr[nt] = load_wfrag(W2, k0, colbase + nt * 16 + ncol);
    }
#pragma unroll
    for (int nt = 0; nt < 4; ++nt) {
      acc2[0][nt] = __builtin_amdgcn_mfma_f32_16x16x32_bf16(a0, bfr[nt], acc2[0][nt], 0, 0, 0);
      acc2[1][nt] = __builtin_amdgcn_mfma_f32_16x16x32_bf16(a1, bfr[nt], acc2[1][nt], 0, 0, 0);
    }
  }

#pragma unroll
  for (int mt = 0; mt < 2; ++mt)
#pragma unroll
    for (int nt = 0; nt < 4; ++nt) {
      int col = colbase + nt * 16 + ncol;
      float bv = b2[col];
#pragma unroll
      for (int r = 0; r < 4; ++r) {
        int row = mt * 16 + (lane >> 4) * 4 + r;
        int grow = r0 + row;
        if (grow < N) {
          size_t idx = (size_t)grow * HNF + col;
          float res = acc2[mt][nt][r] + bv + hh[idx];   // f32 residual
          __builtin_nontemporal_store(res, &h_out[idx]);
        }
      }
    }
}

extern "C" void kernel_launch(void* const* d_in, const int* in_sizes, int n_in,
                              void* d_out, int out_size, void* d_ws, size_t ws_size,
                              hipStream_t stream) {
  const float* x     = (const float*)d_in[0];
  const float* trans = (const float*)d_in[1];
  const float* edge  = (const float*)d_in[2];
  const float* hh    = (const float*)d_in[3];
  const float* W1    = (const float*)d_in[4];
  const float* b1    = (const float*)d_in[5];
  const float* W2    = (const float*)d_in[6];
  const float* b2    = (const float*)d_in[7];

  int N = in_sizes[0] / 3;
  float* coord_out = (float*)d_out;
  float* h_out = coord_out + (size_t)N * 3;

  int grid = (N + MT - 1) / MT;
  bool pre = ws_size >= WS_NEEDED;
  short* wb = (short*)d_ws;

  if (pre) {
    convw<<<(W1ELEMS + W2ELEMS) / 256, 256, 0, stream>>>(W1, W2, wb);
    agg_fused<true><<<grid, 256, 0, stream>>>(x, trans, edge, hh, W1, b1, W2, b2,
                                              wb, coord_out, h_out, N);
  } else {
    agg_fused<false><<<grid, 256, 0, stream>>>(x, trans, edge, hh, W1, b1, W2, b2,
                                               wb, coord_out, h_out, N);
  }
}